// Round 13
// baseline (4110.947 us; speedup 1.0000x reference)
//
#include <hip/hip_runtime.h>
#include <hip/hip_bf16.h>

#define N_DIM 1024
#define R_DIM 6
#define B_DIM 64
#define T_DIM 400
#define NBLK 32

typedef short bf16x8 __attribute__((ext_vector_type(8)));
typedef float f32x4 __attribute__((ext_vector_type(4)));

__device__ inline unsigned short f2bf(float f) {
    unsigned int u = __float_as_uint(f);
    unsigned int r = (u + 0x7fffu + ((u >> 16) & 1u)) >> 16;
    return (unsigned short)r;
}

// Build W in MFMA B-fragment layout, bf16.
// WF[gg][s][lane][i] = W[16gg + (lane&15)][32s + (lane>>4)*8 + i]
// Every block also zeroes its slice of the f32 exchange buffer with
// write-through stores (MALL holds zeros — replay-safe, no flush reliance).
__global__ void __launch_bounds__(64) build_wf(
    const float* __restrict__ lv,
    const float* __restrict__ rv,
    const float* __restrict__ noise,
    unsigned short* __restrict__ wf,
    float* __restrict__ abuf)          // [2][B][N] f32 = 131072 words
{
    int blk = blockIdx.x;
    int l = threadIdx.x;
    {
        float* z = abuf + blk * 64 + l;   // grid 2048*64 = 131072 exactly
        float zero = 0.f;
        asm volatile("global_store_dword %0, %1, off sc0 sc1"
                     :: "v"(z), "v"(zero) : "memory");
    }
    int gg = blk >> 5;
    int s = blk & 31;
    int j = gg * 16 + (l & 15);
    int n0 = s * 32 + (l >> 4) * 8;
    unsigned short* dst = wf + ((size_t)blk * 64 + l) * 8;
    float rj[R_DIM];
#pragma unroll
    for (int k = 0; k < R_DIM; ++k) rj[k] = rv[k * N_DIM + j];
#pragma unroll
    for (int i = 0; i < 8; ++i) {
        int n = n0 + i;
        float acc = noise[j * N_DIM + n];
        float dot = 0.f;
#pragma unroll
        for (int k = 0; k < R_DIM; ++k) dot += rj[k] * lv[k * N_DIM + n];
        acc += dot * (1.0f / (float)N_DIM);
        dst[i] = f2bf(acc);
    }
}

__device__ __forceinline__ unsigned cvtpk(float a, float b) {
    unsigned r;
    asm("v_cvt_pk_bf16_f32 %0, %1, %2" : "=v"(r) : "v"(a), "v"(b));
    return r;
}
__device__ __forceinline__ bf16x8 pack8(f32x4 A, f32x4 B) {
    union { unsigned u[4]; bf16x8 v; } r;
    r.u[0] = cvtpk(A[0], A[1]); r.u[1] = cvtpk(A[2], A[3]);
    r.u[2] = cvtpk(B[0], B[1]); r.u[3] = cvtpk(B[2], B[3]);
    return r.v;
}

// all 64 floats of a bank >= th, wave-uniform verdict
__device__ __forceinline__ bool validg(const f32x4* b, float th) {
    float m = b[0][0];
#pragma unroll
    for (int i = 0; i < 16; ++i) {
        f32x4 v = b[i];
        m = fminf(m, fminf(fminf(v[0], v[1]), fminf(v[2], v[3])));
    }
    return __all(m >= th);
}

// MALL-coherent 16B load into bank slot (offset within one 8-frag group)
#define LOADB(bank, slot, off, P)                                              \
    asm volatile("global_load_dwordx4 %0, %1, off offset:" #off " sc0 sc1"     \
                 : "=v"(bank[slot]) : "v"(P) : "memory");
#define ISSUE_GROUP(bank, P)                                                   \
    LOADB(bank, 0, 0, P)    LOADB(bank, 1, 16, P)                              \
    LOADB(bank, 2, 128, P)  LOADB(bank, 3, 144, P)                             \
    LOADB(bank, 4, 256, P)  LOADB(bank, 5, 272, P)                             \
    LOADB(bank, 6, 384, P)  LOADB(bank, 7, 400, P)                             \
    LOADB(bank, 8, 512, P)  LOADB(bank, 9, 528, P)                             \
    LOADB(bank, 10, 640, P) LOADB(bank, 11, 656, P)                            \
    LOADB(bank, 12, 768, P) LOADB(bank, 13, 784, P)                            \
    LOADB(bank, 14, 896, P) LOADB(bank, 15, 912, P)

// rare path: re-poll one group until its data is fresh
#define RETRY(bank, P, TH)                                                     \
    while (!ok) {                                                              \
        __builtin_amdgcn_s_sleep(1);                                           \
        ISSUE_GROUP(bank, P)                                                   \
        asm volatile("s_waitcnt vmcnt(0)" ::: "memory");                       \
        __builtin_amdgcn_sched_barrier(0);                                     \
        ok = validg(bank, TH);                                                 \
    }

// decode (subtract base), pack to bf16, two col-tile MFMAs
#define MM1(bank, i, sg, A0, A1) {                                             \
    f32x4 lo = bank[2 * (i)] - bf4;                                            \
    f32x4 hi = bank[2 * (i) + 1] - bf4;                                        \
    bf16x8 afr = pack8(lo, hi);                                                \
    A0 = __builtin_amdgcn_mfma_f32_16x16x32_bf16(afr, wfrag[(sg) * 64 + l],        A0, 0, 0, 0); \
    A1 = __builtin_amdgcn_mfma_f32_16x16x32_bf16(afr, wfrag[(32 + (sg)) * 64 + l], A1, 0, 0, 0); }
#define MMG8(bank, s0)                                                         \
    MM1(bank, 0, (s0) + 0, a0e, a1e) MM1(bank, 1, (s0) + 1, a0o, a1o)          \
    MM1(bank, 2, (s0) + 2, a0e, a1e) MM1(bank, 3, (s0) + 3, a0o, a1o)          \
    MM1(bank, 4, (s0) + 4, a0e, a1e) MM1(bank, 5, (s0) + 5, a0o, a1o)          \
    MM1(bank, 6, (s0) + 6, a0e, a1e) MM1(bank, 7, (s0) + 7, a0o, a1o)

#define LOADX(i, P)                                                            \
    asm volatile("global_load_dword %0, %1, off" : "=v"(x[i]) : "v"(P) : "memory");

// 32 blocks x 256 threads. Block g owns jcols [32g,32g+32) (W 64 KB LDS).
// Wave w = batch band [16w,16w+16); bands independent. DATA-AS-FLAG protocol:
// a_t published as f32 (a + 3(t+1)) via write-through stores (no drain, no
// tags); consumers validate v >= 3(t+1)-1 group-by-group, pipelined. One
// MALL round trip per step on the critical path.
__global__ void __launch_bounds__(256, 1) rnn_recurrence(
    const float* __restrict__ hidden0,
    const float* __restrict__ input,        // [B][T][N]
    const unsigned short* __restrict__ wf,
    float* __restrict__ out_hidden,         // [T][B][N]
    float* __restrict__ abuf)               // [2][B][N] f32 exchange
{
    const int g = blockIdx.x;
    const int tid = threadIdx.x;
    const int w = tid >> 6;          // band
    const int l = tid & 63;
    const int brow0 = w * 16 + (l >> 4) * 4;

    // ---- stage this block's W slice (32 jcols = 64 KB) into LDS ----
    __shared__ __align__(16) unsigned short wlds[32 * 1024];
    {
        const bf16x8* src = reinterpret_cast<const bf16x8*>(wf) + (size_t)g * 4096;
        bf16x8* dstl = reinterpret_cast<bf16x8*>(wlds);
#pragma unroll
        for (int i = 0; i < 16; ++i)
            dstl[tid + i * 256] = src[tid + i * 256];
    }
    __syncthreads();
    const bf16x8* wfrag = reinterpret_cast<const bf16x8*>(wlds);

    int jc[2];
#pragma unroll
    for (int nt = 0; nt < 2; ++nt) jc[nt] = g * 32 + nt * 16 + (l & 15);

    // ---- init h & publish encoded a_0 (base 3.0) — fire and forget ----
    float h[8];
#pragma unroll
    for (int nt = 0; nt < 2; ++nt) {
        float h0v = hidden0[jc[nt]];
#pragma unroll
        for (int i = 0; i < 4; ++i) h[nt * 4 + i] = h0v;
    }
#pragma unroll
    for (int nt = 0; nt < 2; ++nt)
#pragma unroll
        for (int i = 0; i < 4; ++i) {
            float v = tanhf(h[nt * 4 + i]) + 3.0f;
            float* addr = abuf + (brow0 + i) * N_DIM + jc[nt];
            asm volatile("global_store_dword %0, %1, off sc0 sc1"
                         :: "v"(addr), "v"(v) : "memory");
        }

    const int af_off = (w * 16 + (l & 15)) * N_DIM + (l >> 4) * 8;

    for (int t = 0; t < T_DIM; ++t) {
        const float base = 3.0f * (float)(t + 1);
        const float th = base - 1.0f;
        const f32x4 bf4 = {base, base, base, base};
        const float* abase = abuf + (size_t)(t & 1) * (B_DIM * N_DIM) + af_off;
        const float* p0 = abase;
        const float* p1 = abase + 256;
        const float* p2 = abase + 512;
        const float* p3 = abase + 768;

        // x loads (8, issued first — drained by the final vmcnt(0))
        float x[8];
#pragma unroll
        for (int nt = 0; nt < 2; ++nt)
#pragma unroll
            for (int i = 0; i < 4; ++i) {
                const float* xp = input + ((size_t)(brow0 + i) * T_DIM + t) * N_DIM + jc[nt];
                LOADX(nt * 4 + i, xp)
            }

        f32x4 bA[16], bB[16];
        ISSUE_GROUP(bA, p0)
        ISSUE_GROUP(bB, p1)

        f32x4 a0e = {0.f, 0.f, 0.f, 0.f};
        f32x4 a0o = {0.f, 0.f, 0.f, 0.f};
        f32x4 a1e = {0.f, 0.f, 0.f, 0.f};
        f32x4 a1o = {0.f, 0.f, 0.f, 0.f};

        asm volatile("s_waitcnt vmcnt(16)" ::: "memory");   // G0 arrived
        __builtin_amdgcn_sched_barrier(0);
        bool ok = validg(bA, th);
        RETRY(bA, p0, th)
        MMG8(bA, 0)
        ISSUE_GROUP(bA, p2)
        asm volatile("s_waitcnt vmcnt(16)" ::: "memory");   // G1 arrived
        __builtin_amdgcn_sched_barrier(0);
        ok = validg(bB, th);
        RETRY(bB, p1, th)
        MMG8(bB, 8)
        ISSUE_GROUP(bB, p3)
        asm volatile("s_waitcnt vmcnt(16)" ::: "memory");   // G2 arrived
        __builtin_amdgcn_sched_barrier(0);
        ok = validg(bA, th);
        RETRY(bA, p2, th)
        MMG8(bA, 16)
        asm volatile("s_waitcnt vmcnt(0)" ::: "memory");    // G3 + x arrived
        __builtin_amdgcn_sched_barrier(0);
        ok = validg(bB, th);
        RETRY(bB, p3, th)
        MMG8(bB, 24)

        f32x4 acc0 = a0e + a0o;
        f32x4 acc1 = a1e + a1o;

        // ---- h update + activation ----
        float a[8];
#pragma unroll
        for (int i = 0; i < 4; ++i) {
            float hn;
            hn = 0.9f * h[0 + i] + 0.1f * (acc0[i] + x[0 + i]); h[0 + i] = hn; a[0 + i] = tanhf(hn);
            hn = 0.9f * h[4 + i] + 0.1f * (acc1[i] + x[4 + i]); h[4 + i] = hn; a[4 + i] = tanhf(hn);
        }

        // ---- publish encoded a_{t+1} (base+3) — fire and forget ----
        {
            float* nbuf = abuf + (size_t)((t + 1) & 1) * (B_DIM * N_DIM);
            float bnext = base + 3.0f;
#pragma unroll
            for (int nt = 0; nt < 2; ++nt)
#pragma unroll
                for (int i = 0; i < 4; ++i) {
                    float v = a[nt * 4 + i] + bnext;
                    float* addr = nbuf + (brow0 + i) * N_DIM + jc[nt];
                    asm volatile("global_store_dword %0, %1, off sc0 sc1"
                                 :: "v"(addr), "v"(v) : "memory");
                }
        }

        // out_hidden stores (plain cached; off the exchange critical path)
#pragma unroll
        for (int nt = 0; nt < 2; ++nt)
#pragma unroll
            for (int i = 0; i < 4; ++i)
                out_hidden[((size_t)t * B_DIM + (brow0 + i)) * N_DIM + jc[nt]] = a[nt * 4 + i];
    }
}

__global__ void __launch_bounds__(256) geo_kernel(
    const float* __restrict__ hid,
    const float* __restrict__ gW,
    const float* __restrict__ gb,
    const float* __restrict__ rW,
    float* __restrict__ geo,
    float* __restrict__ ro)
{
    int row = blockIdx.x * 4 + (threadIdx.x >> 6);
    int l = threadIdx.x & 63;
    const float* hrow = hid + (size_t)row * N_DIM;
    float a0 = 0.f, a1 = 0.f;
#pragma unroll
    for (int i = 0; i < N_DIM / 64; ++i) {
        int idx = i * 64 + l;
        float th = tanhf(hrow[idx]);
        a0 += th * gW[idx];
        a1 += th * gW[N_DIM + idx];
    }
#pragma unroll
    for (int off = 32; off; off >>= 1) {
        a0 += __shfl_down(a0, off);
        a1 += __shfl_down(a1, off);
    }
    if (l == 0) {
        float g0 = a0 + gb[0];
        float g1 = a1 + gb[1];
        geo[(size_t)row * 2 + 0] = g0;
        geo[(size_t)row * 2 + 1] = g1;
#pragma unroll
        for (int m = 0; m < 6; ++m)
            ro[(size_t)row * 6 + m] = g0 * rW[m * 2] + g1 * rW[m * 2 + 1];
    }
}

extern "C" void kernel_launch(void* const* d_in, const int* in_sizes, int n_in,
                              void* d_out, int out_size, void* d_ws, size_t ws_size,
                              hipStream_t stream) {
    const float* hidden0 = (const float*)d_in[0];
    const float* input   = (const float*)d_in[1];
    const float* lv      = (const float*)d_in[2];
    const float* rv      = (const float*)d_in[3];
    const float* noise   = (const float*)d_in[4];
    const float* gW      = (const float*)d_in[5];
    const float* gb      = (const float*)d_in[6];
    const float* rW      = (const float*)d_in[7];

    float* out_hidden = (float*)d_out;
    float* geo = out_hidden + (size_t)T_DIM * B_DIM * N_DIM;
    float* ro  = geo + (size_t)T_DIM * B_DIM * 2;

    unsigned short* wf = (unsigned short*)d_ws;                     // 2 MB
    float* abuf = (float*)(wf + (size_t)64 * 32 * 64 * 8);          // 512 KB f32 [2][B][N]

    build_wf<<<2048, 64, 0, stream>>>(lv, rv, noise, wf, abuf);

    void* args[] = { (void*)&hidden0, (void*)&input, (void*)&wf,
                     (void*)&out_hidden, (void*)&abuf };
    hipError_t e = hipLaunchCooperativeKernel((const void*)rnn_recurrence,
                                              dim3(NBLK), dim3(256), args, 0, stream);
    if (e != hipSuccess) {
        rnn_recurrence<<<dim3(NBLK), dim3(256), 0, stream>>>(
            hidden0, input, wf, out_hidden, abuf);
    }

    geo_kernel<<<(T_DIM * B_DIM) / 4, 256, 0, stream>>>(out_hidden, gW, gb, rW, geo, ro);
}

// Round 15
// 1508.843 us; speedup vs baseline: 2.7246x; 2.7246x over previous
//
#include <hip/hip_runtime.h>
#include <hip/hip_bf16.h>

#define N_DIM 1024
#define R_DIM 6
#define B_DIM 64
#define T_DIM 400
#define NBLK 128   // 4 bands x 32 jcol-groups, ONE wave per block

typedef short bf16x8 __attribute__((ext_vector_type(8)));
typedef float f32x4 __attribute__((ext_vector_type(4)));

__device__ inline unsigned short f2bf(float f) {
    unsigned int u = __float_as_uint(f);
    unsigned int r = (u + 0x7fffu + ((u >> 16) & 1u)) >> 16;
    return (unsigned short)r;
}

// Build W in MFMA B-fragment layout, bf16.
// WF[gg][s][lane][i] = W[16gg + (lane&15)][32s + (lane>>4)*8 + i]
// Block 0 zeroes the 4096-word mailbox array (4 bands x 32 consumers x 32
// producers), deterministic per launch.
__global__ void __launch_bounds__(64) build_wf(
    const float* __restrict__ lv,
    const float* __restrict__ rv,
    const float* __restrict__ noise,
    unsigned short* __restrict__ wf,
    unsigned* __restrict__ mbox)
{
    int blk = blockIdx.x;
    int l = threadIdx.x;
    if (blk == 0) {
#pragma unroll
        for (int k = 0; k < 64; ++k) mbox[k * 64 + l] = 0u;
    }
    int gg = blk >> 5;
    int s = blk & 31;
    int j = gg * 16 + (l & 15);
    int n0 = s * 32 + (l >> 4) * 8;
    unsigned short* dst = wf + ((size_t)blk * 64 + l) * 8;
    float rj[R_DIM];
#pragma unroll
    for (int k = 0; k < R_DIM; ++k) rj[k] = rv[k * N_DIM + j];
#pragma unroll
    for (int i = 0; i < 8; ++i) {
        int n = n0 + i;
        float acc = noise[j * N_DIM + n];
        float dot = 0.f;
#pragma unroll
        for (int k = 0; k < R_DIM; ++k) dot += rj[k] * lv[k * N_DIM + n];
        acc += dot * (1.0f / (float)N_DIM);
        dst[i] = f2bf(acc);
    }
}

// Publish one 16x16 tile slice: rows brow0..brow0+3, col jcol. Full-wave,
// non-atomic, write-through (sc0 sc1). Pair transpose (verified R6/R9/R11).
__device__ __forceinline__ void publish_tile(unsigned short* dst, const float a[4],
                                             int brow0, int jcol, int l) {
    unsigned* d32 = (unsigned*)dst;
    int odd = l & 1;
    int j0 = jcol & ~1;
#pragma unroll
    for (int k = 0; k < 2; ++k) {
        float send = odd ? a[k] : a[k + 2];
        float got = __shfl_xor(send, 1);
        int row = brow0 + (odd ? (k + 2) : k);
        unsigned lo = odd ? f2bf(got)      : f2bf(a[k]);     // col j0
        unsigned hi = odd ? f2bf(a[k + 2]) : f2bf(got);      // col j0+1
        unsigned pk = lo | (hi << 16);
        unsigned* addr = d32 + ((row * N_DIM + j0) >> 1);
        asm volatile("global_store_dword %0, %1, off sc0 sc1"
                     :: "v"(addr), "v"(pk) : "memory");
    }
}

// Producer multicast: lanes 0..31 store the tag to each consumer's private
// mailbox word. mbox[w][consumer][producer]. (R11, proven)
__device__ __forceinline__ void push_tag(unsigned* mbox, int w, int g, unsigned val, int l) {
    if (l < 32) {
        unsigned* addr = mbox + (w * 1024 + l * 32 + g);
        asm volatile("global_store_dword %0, %1, off sc0 sc1"
                     :: "v"(addr), "v"(val) : "memory");
    }
}

// Poll own private mailbox row (32 dwords, single-reader). (R11, proven)
__device__ __forceinline__ void poll_mbox(const unsigned* myrow, unsigned target, int l) {
    const unsigned* p = myrow + (l & 31);
    for (;;) {
        unsigned v;
        asm volatile("global_load_dword %0, %1, off sc0 sc1\n\t"
                     "s_waitcnt vmcnt(0)"
                     : "=v"(v) : "v"(p) : "memory");
        if (__all(v >= target)) break;
        __builtin_amdgcn_s_sleep(1);
    }
}

// Coherent 16B load into av slot.
#define LOADA(slot, off)                                                       \
    asm volatile("global_load_dwordx4 %0, %1, off offset:" #off " sc0 sc1"     \
                 : "=v"(av[slot]) : "v"(ap) : "memory");

// Plain cached x load.
#define LOADX(i, P)                                                            \
    asm volatile("global_load_dword %0, %1, off" : "=v"(x[i]) : "v"(P) : "memory");

// One k-chunk s: A-fragment av[s] feeds both column tiles (nt=0,1).
#define MFMA_S(s, A0, A1)                                                      \
    A0 = __builtin_amdgcn_mfma_f32_16x16x32_bf16(av[s], wfrag[(s) * 64 + l],        A0, 0, 0, 0); \
    A1 = __builtin_amdgcn_mfma_f32_16x16x32_bf16(av[s], wfrag[(32 + (s)) * 64 + l], A1, 0, 0, 0);

// 128 blocks x 64 threads (ONE wave per block => one wave per CU; private
// L2 port, no sibling-wave contention). Block (w,g): band w = batch rows
// [16w,16w+16), jcols [32g,32g+32) (W slice 64 KB static LDS). Bands are
// independent chains; sync = R11's private-mailbox protocol, unchanged.
__global__ void __launch_bounds__(64, 1) rnn_recurrence(
    const float* __restrict__ hidden0,
    const float* __restrict__ input,        // [B][T][N]
    const unsigned short* __restrict__ wf,
    float* __restrict__ out_hidden,         // [T][B][N]
    unsigned short* __restrict__ abuf0,
    unsigned short* __restrict__ abuf1,
    unsigned* __restrict__ mbox)
{
    const int w = blockIdx.x >> 5;   // band
    const int g = blockIdx.x & 31;   // jcol group
    const int l = threadIdx.x;       // 0..63
    const int brow0 = w * 16 + (l >> 4) * 4;

    // ---- stage this block's W slice (32 jcols = 64 KB) into LDS ----
    __shared__ __align__(16) unsigned short wlds[32 * 1024];
    {
        const bf16x8* src = reinterpret_cast<const bf16x8*>(wf) + (size_t)g * 4096;
        bf16x8* dstl = reinterpret_cast<bf16x8*>(wlds);
#pragma unroll
        for (int i = 0; i < 64; ++i)
            dstl[l + i * 64] = src[l + i * 64];
    }
    __syncthreads();
    const bf16x8* wfrag = reinterpret_cast<const bf16x8*>(wlds);

    int jc[2];
#pragma unroll
    for (int nt = 0; nt < 2; ++nt) jc[nt] = g * 32 + nt * 16 + (l & 15);

    // ---- init h & publish a0, push tag 1 ----
    float h[8];   // h[nt*4+i]
#pragma unroll
    for (int nt = 0; nt < 2; ++nt) {
        float h0v = hidden0[jc[nt]];
#pragma unroll
        for (int i = 0; i < 4; ++i) h[nt * 4 + i] = h0v;
    }
    {
        float a0[8];
#pragma unroll
        for (int k = 0; k < 8; ++k) a0[k] = tanhf(h[k]);
#pragma unroll
        for (int nt = 0; nt < 2; ++nt)
            publish_tile(abuf0, &a0[nt * 4], brow0, jc[nt], l);
        asm volatile("s_waitcnt vmcnt(0)" ::: "memory");
        push_tag(mbox, w, g, 1u, l);
    }

    const int aoff_us = (w * 16 + (l & 15)) * N_DIM + (l >> 4) * 8;
    const unsigned* myrow = mbox + (w * 1024 + g * 32);

    for (int t = 0; t < T_DIM; ++t) {
        const unsigned short* acur = (t & 1) ? abuf1 : abuf0;
        unsigned short* anext = (t & 1) ? abuf0 : abuf1;
        const unsigned short* ap = acur + aoff_us;

        // wait until all 32 producers of this band pushed tag t+1
        poll_mbox(myrow, (unsigned)(t + 1), l);

        // ---- issue ALL 32 a-loads (oldest in queue) ----
        bf16x8 av[32];
        LOADA(0, 0)     LOADA(1, 64)    LOADA(2, 128)   LOADA(3, 192)
        LOADA(4, 256)   LOADA(5, 320)   LOADA(6, 384)   LOADA(7, 448)
        LOADA(8, 512)   LOADA(9, 576)   LOADA(10, 640)  LOADA(11, 704)
        LOADA(12, 768)  LOADA(13, 832)  LOADA(14, 896)  LOADA(15, 960)
        LOADA(16, 1024) LOADA(17, 1088) LOADA(18, 1152) LOADA(19, 1216)
        LOADA(20, 1280) LOADA(21, 1344) LOADA(22, 1408) LOADA(23, 1472)
        LOADA(24, 1536) LOADA(25, 1600) LOADA(26, 1664) LOADA(27, 1728)
        LOADA(28, 1792) LOADA(29, 1856) LOADA(30, 1920) LOADA(31, 1984)

        // ---- x loads for this step (youngest; hide under MFMA phases) ----
        float x[8];
#pragma unroll
        for (int nt = 0; nt < 2; ++nt)
#pragma unroll
            for (int i = 0; i < 4; ++i) {
                const float* xp = input + ((size_t)(brow0 + i) * T_DIM + t) * N_DIM + jc[nt];
                LOADX(nt * 4 + i, xp)
            }

        f32x4 a0e = {0.f, 0.f, 0.f, 0.f};
        f32x4 a0o = {0.f, 0.f, 0.f, 0.f};
        f32x4 a1e = {0.f, 0.f, 0.f, 0.f};
        f32x4 a1o = {0.f, 0.f, 0.f, 0.f};

        // 40 outstanding; oldest-first accounting (m135):
        asm volatile("s_waitcnt vmcnt(32)" ::: "memory");   // a0..7 done
        __builtin_amdgcn_sched_barrier(0);
        MFMA_S(0, a0e, a1e) MFMA_S(1, a0o, a1o) MFMA_S(2, a0e, a1e) MFMA_S(3, a0o, a1o)
        MFMA_S(4, a0e, a1e) MFMA_S(5, a0o, a1o) MFMA_S(6, a0e, a1e) MFMA_S(7, a0o, a1o)
        asm volatile("s_waitcnt vmcnt(24)" ::: "memory");   // a8..15 done
        __builtin_amdgcn_sched_barrier(0);
        MFMA_S(8, a0e, a1e)  MFMA_S(9, a0o, a1o)  MFMA_S(10, a0e, a1e) MFMA_S(11, a0o, a1o)
        MFMA_S(12, a0e, a1e) MFMA_S(13, a0o, a1o) MFMA_S(14, a0e, a1e) MFMA_S(15, a0o, a1o)
        asm volatile("s_waitcnt vmcnt(16)" ::: "memory");   // a16..23 done
        __builtin_amdgcn_sched_barrier(0);
        MFMA_S(16, a0e, a1e) MFMA_S(17, a0o, a1o) MFMA_S(18, a0e, a1e) MFMA_S(19, a0o, a1o)
        MFMA_S(20, a0e, a1e) MFMA_S(21, a0o, a1o) MFMA_S(22, a0e, a1e) MFMA_S(23, a0o, a1o)
        asm volatile("s_waitcnt vmcnt(8)" ::: "memory");    // a24..31 done
        __builtin_amdgcn_sched_barrier(0);
        MFMA_S(24, a0e, a1e) MFMA_S(25, a0o, a1o) MFMA_S(26, a0e, a1e) MFMA_S(27, a0o, a1o)
        MFMA_S(28, a0e, a1e) MFMA_S(29, a0o, a1o) MFMA_S(30, a0e, a1e) MFMA_S(31, a0o, a1o)

        asm volatile("s_waitcnt vmcnt(0)" ::: "memory");    // x done
        __builtin_amdgcn_sched_barrier(0);

        f32x4 acc0 = a0e + a0o;
        f32x4 acc1 = a1e + a1o;

        // ---- h update + activation ----
        float a[8];
#pragma unroll
        for (int i = 0; i < 4; ++i) {
            float hn;
            hn = 0.9f * h[0 + i] + 0.1f * (acc0[i] + x[0 + i]); h[0 + i] = hn; a[0 + i] = tanhf(hn);
            hn = 0.9f * h[4 + i] + 0.1f * (acc1[i] + x[4 + i]); h[4 + i] = hn; a[4 + i] = tanhf(hn);
        }

        if (t + 1 < T_DIM) {
#pragma unroll
            for (int nt = 0; nt < 2; ++nt)
                publish_tile(anext, &a[nt * 4], brow0, jc[nt], l);
            asm volatile("s_waitcnt vmcnt(0)" ::: "memory");   // publishes at MALL
            push_tag(mbox, w, g, (unsigned)(t + 2), l);
        }
        // out_hidden stores off the critical path (after tag push)
#pragma unroll
        for (int nt = 0; nt < 2; ++nt)
#pragma unroll
            for (int i = 0; i < 4; ++i)
                out_hidden[((size_t)t * B_DIM + (brow0 + i)) * N_DIM + jc[nt]] = a[nt * 4 + i];
    }
}

__global__ void __launch_bounds__(256) geo_kernel(
    const float* __restrict__ hid,
    const float* __restrict__ gW,
    const float* __restrict__ gb,
    const float* __restrict__ rW,
    float* __restrict__ geo,
    float* __restrict__ ro)
{
    int row = blockIdx.x * 4 + (threadIdx.x >> 6);
    int l = threadIdx.x & 63;
    const float* hrow = hid + (size_t)row * N_DIM;
    float a0 = 0.f, a1 = 0.f;
#pragma unroll
    for (int i = 0; i < N_DIM / 64; ++i) {
        int idx = i * 64 + l;
        float th = tanhf(hrow[idx]);
        a0 += th * gW[idx];
        a1 += th * gW[N_DIM + idx];
    }
#pragma unroll
    for (int off = 32; off; off >>= 1) {
        a0 += __shfl_down(a0, off);
        a1 += __shfl_down(a1, off);
    }
    if (l == 0) {
        float g0 = a0 + gb[0];
        float g1 = a1 + gb[1];
        geo[(size_t)row * 2 + 0] = g0;
        geo[(size_t)row * 2 + 1] = g1;
#pragma unroll
        for (int m = 0; m < 6; ++m)
            ro[(size_t)row * 6 + m] = g0 * rW[m * 2] + g1 * rW[m * 2 + 1];
    }
}

extern "C" void kernel_launch(void* const* d_in, const int* in_sizes, int n_in,
                              void* d_out, int out_size, void* d_ws, size_t ws_size,
                              hipStream_t stream) {
    const float* hidden0 = (const float*)d_in[0];
    const float* input   = (const float*)d_in[1];
    const float* lv      = (const float*)d_in[2];
    const float* rv      = (const float*)d_in[3];
    const float* noise   = (const float*)d_in[4];
    const float* gW      = (const float*)d_in[5];
    const float* gb      = (const float*)d_in[6];
    const float* rW      = (const float*)d_in[7];

    float* out_hidden = (float*)d_out;
    float* geo = out_hidden + (size_t)T_DIM * B_DIM * N_DIM;
    float* ro  = geo + (size_t)T_DIM * B_DIM * 2;

    unsigned short* wf    = (unsigned short*)d_ws;                  // 2 MB
    unsigned short* abuf0 = wf + (size_t)64 * 32 * 64 * 8;          // 128 KB
    unsigned short* abuf1 = abuf0 + (size_t)B_DIM * N_DIM;          // 128 KB
    unsigned* mbox = (unsigned*)(abuf1 + (size_t)B_DIM * N_DIM);    // 16 KB

    build_wf<<<2048, 64, 0, stream>>>(lv, rv, noise, wf, mbox);

    void* args[] = { (void*)&hidden0, (void*)&input, (void*)&wf,
                     (void*)&out_hidden, (void*)&abuf0, (void*)&abuf1, (void*)&mbox };
    hipError_t e = hipLaunchCooperativeKernel((const void*)rnn_recurrence,
                                              dim3(NBLK), dim3(64), args, 0, stream);
    if (e != hipSuccess) {
        // 128 blocks, 64 KB LDS each: capacity 2/CU x 256 CUs >= 128 —
        // co-resident under plain launch as well.
        rnn_recurrence<<<dim3(NBLK), dim3(64), 0, stream>>>(
            hidden0, input, wf, out_hidden, abuf0, abuf1, mbox);
    }

    geo_kernel<<<(T_DIM * B_DIM) / 4, 256, 0, stream>>>(out_hidden, gW, gb, rW, geo, ro);
}

// Round 16
// 1325.480 us; speedup vs baseline: 3.1015x; 1.1383x over previous
//
#include <hip/hip_runtime.h>
#include <hip/hip_bf16.h>

#define N_DIM 1024
#define R_DIM 6
#define B_DIM 64
#define T_DIM 400
#define NBLK 128   // 4 bands x 32 jcol-groups, ONE wave per block

typedef short bf16x8 __attribute__((ext_vector_type(8)));
typedef float f32x4 __attribute__((ext_vector_type(4)));

__device__ inline unsigned short f2bf(float f) {
    unsigned int u = __float_as_uint(f);
    unsigned int r = (u + 0x7fffu + ((u >> 16) & 1u)) >> 16;
    return (unsigned short)r;
}

// fast tanh: (e^{2x}-1)/(e^{2x}+1); |x| <= ~12 here so no overflow.
__device__ __forceinline__ float ftanh(float v) {
    float e = __expf(2.0f * v);
    return (e - 1.0f) * __builtin_amdgcn_rcpf(e + 1.0f);
}

// Build W in MFMA B-fragment layout, bf16.
// WF[gg][s][lane][i] = W[16gg + (lane&15)][32s + (lane>>4)*8 + i]
// Block 0 zeroes the 4096-word mailbox array.
__global__ void __launch_bounds__(64) build_wf(
    const float* __restrict__ lv,
    const float* __restrict__ rv,
    const float* __restrict__ noise,
    unsigned short* __restrict__ wf,
    unsigned* __restrict__ mbox)
{
    int blk = blockIdx.x;
    int l = threadIdx.x;
    if (blk == 0) {
#pragma unroll
        for (int k = 0; k < 64; ++k) mbox[k * 64 + l] = 0u;
    }
    int gg = blk >> 5;
    int s = blk & 31;
    int j = gg * 16 + (l & 15);
    int n0 = s * 32 + (l >> 4) * 8;
    unsigned short* dst = wf + ((size_t)blk * 64 + l) * 8;
    float rj[R_DIM];
#pragma unroll
    for (int k = 0; k < R_DIM; ++k) rj[k] = rv[k * N_DIM + j];
#pragma unroll
    for (int i = 0; i < 8; ++i) {
        int n = n0 + i;
        float acc = noise[j * N_DIM + n];
        float dot = 0.f;
#pragma unroll
        for (int k = 0; k < R_DIM; ++k) dot += rj[k] * lv[k * N_DIM + n];
        acc += dot * (1.0f / (float)N_DIM);
        dst[i] = f2bf(acc);
    }
}

// Publish one 16x16 tile slice (pair transpose; verified R6/R9/R11/R15).
__device__ __forceinline__ void publish_tile(unsigned short* dst, const float a[4],
                                             int brow0, int jcol, int l) {
    unsigned* d32 = (unsigned*)dst;
    int odd = l & 1;
    int j0 = jcol & ~1;
#pragma unroll
    for (int k = 0; k < 2; ++k) {
        float send = odd ? a[k] : a[k + 2];
        float got = __shfl_xor(send, 1);
        int row = brow0 + (odd ? (k + 2) : k);
        unsigned lo = odd ? f2bf(got)      : f2bf(a[k]);
        unsigned hi = odd ? f2bf(a[k + 2]) : f2bf(got);
        unsigned pk = lo | (hi << 16);
        unsigned* addr = d32 + ((row * N_DIM + j0) >> 1);
        asm volatile("global_store_dword %0, %1, off sc0 sc1"
                     :: "v"(addr), "v"(pk) : "memory");
    }
}

// Producer multicast tags (R11, proven).
__device__ __forceinline__ void push_tag(unsigned* mbox, int w, int g, unsigned val, int l) {
    if (l < 32) {
        unsigned* addr = mbox + (w * 1024 + l * 32 + g);
        asm volatile("global_store_dword %0, %1, off sc0 sc1"
                     :: "v"(addr), "v"(val) : "memory");
    }
}

#define LOADA(slot, off)                                                       \
    asm volatile("global_load_dwordx4 %0, %1, off offset:" #off " sc0 sc1"     \
                 : "=v"(av[slot]) : "v"(ap) : "memory");
#define LOADX(i, P)                                                            \
    asm volatile("global_load_dword %0, %1, off" : "=v"(xn[i]) : "v"(P) : "memory");
#define LOADP(dst, P)                                                          \
    asm volatile("global_load_dword %0, %1, off sc0 sc1"                       \
                 : "=v"(dst) : "v"(P) : "memory");

#define MFMA_S(s, A0, A1)                                                      \
    A0 = __builtin_amdgcn_mfma_f32_16x16x32_bf16(av[s], wfrag[(s) * 64 + l],        A0, 0, 0, 0); \
    A1 = __builtin_amdgcn_mfma_f32_16x16x32_bf16(av[s], wfrag[(32 + (s)) * 64 + l], A1, 0, 0, 0);

// 128 blocks x 64 threads (one wave per CU — R15 structure, proven).
// Block (w,g): band w rows [16w,16w+16), jcols [32g,32g+32) (W 64 KB LDS).
// R11 mailbox protocol + this round: pipelined 2-deep poll, x-prefetch
// pipeline, out_hidden folded before the drain, fast tanh.
__global__ void __launch_bounds__(64, 1) rnn_recurrence(
    const float* __restrict__ hidden0,
    const float* __restrict__ input,        // [B][T][N]
    const unsigned short* __restrict__ wf,
    float* __restrict__ out_hidden,         // [T][B][N]
    unsigned short* __restrict__ abuf0,
    unsigned short* __restrict__ abuf1,
    unsigned* __restrict__ mbox)
{
    const int w = blockIdx.x >> 5;   // band
    const int g = blockIdx.x & 31;   // jcol group
    const int l = threadIdx.x;       // 0..63
    const int brow0 = w * 16 + (l >> 4) * 4;

    // ---- stage this block's W slice (32 jcols = 64 KB) into LDS ----
    __shared__ __align__(16) unsigned short wlds[32 * 1024];
    {
        const bf16x8* src = reinterpret_cast<const bf16x8*>(wf) + (size_t)g * 4096;
        bf16x8* dstl = reinterpret_cast<bf16x8*>(wlds);
#pragma unroll
        for (int i = 0; i < 64; ++i)
            dstl[l + i * 64] = src[l + i * 64];
    }
    __syncthreads();
    const bf16x8* wfrag = reinterpret_cast<const bf16x8*>(wlds);

    int jc[2];
#pragma unroll
    for (int nt = 0; nt < 2; ++nt) jc[nt] = g * 32 + nt * 16 + (l & 15);

    // ---- init h; prefetch x(0); publish a0; drain; tag 1 ----
    float h[8];
#pragma unroll
    for (int nt = 0; nt < 2; ++nt) {
        float h0v = hidden0[jc[nt]];
#pragma unroll
        for (int i = 0; i < 4; ++i) h[nt * 4 + i] = h0v;
    }
    float x[8], xn[8];
#pragma unroll
    for (int nt = 0; nt < 2; ++nt)
#pragma unroll
        for (int i = 0; i < 4; ++i) {
            const float* xp = input + ((size_t)(brow0 + i) * T_DIM + 0) * N_DIM + jc[nt];
            LOADX(nt * 4 + i, xp)
        }
    {
        float a0[8];
#pragma unroll
        for (int k = 0; k < 8; ++k) a0[k] = ftanh(h[k]);
#pragma unroll
        for (int nt = 0; nt < 2; ++nt)
            publish_tile(abuf0, &a0[nt * 4], brow0, jc[nt], l);
        asm volatile("s_waitcnt vmcnt(0)" ::: "memory");   // x(0) + publishes done
#pragma unroll
        for (int k = 0; k < 8; ++k) x[k] = xn[k];
        push_tag(mbox, w, g, 1u, l);
    }

    const int aoff_us = (w * 16 + (l & 15)) * N_DIM + (l >> 4) * 8;
    const unsigned* myrow = mbox + (w * 1024 + g * 32);
    const unsigned* pollp = myrow + (l & 31);

    for (int t = 0; t < T_DIM; ++t) {
        const unsigned short* acur = (t & 1) ? abuf1 : abuf0;
        unsigned short* anext = (t & 1) ? abuf0 : abuf1;
        const unsigned short* ap = acur + aoff_us;
        const unsigned target = (unsigned)(t + 1);

        // ---- pipelined 2-deep poll (sampling cadence ~RT/2). On exit
        // exactly ONE poll load dangles; it is the OLDEST outstanding op and
        // retires inside the vmcnt(32) below (m135 oldest-first). pv0/pv1
        // are kept live past the drain via the fake use at the bottom. ----
        unsigned pv0, pv1;
        LOADP(pv0, pollp)
        for (;;) {
            LOADP(pv1, pollp)
            asm volatile("s_waitcnt vmcnt(1)" ::: "memory");
            if (__all(pv0 >= target)) break;      // pv1 dangles
            LOADP(pv0, pollp)
            asm volatile("s_waitcnt vmcnt(1)" ::: "memory");
            if (__all(pv1 >= target)) break;      // pv0 dangles
            __builtin_amdgcn_s_sleep(1);
        }

        // ---- issue ALL 32 a-loads (behind the dangling poll) ----
        bf16x8 av[32];
        LOADA(0, 0)     LOADA(1, 64)    LOADA(2, 128)   LOADA(3, 192)
        LOADA(4, 256)   LOADA(5, 320)   LOADA(6, 384)   LOADA(7, 448)
        LOADA(8, 512)   LOADA(9, 576)   LOADA(10, 640)  LOADA(11, 704)
        LOADA(12, 768)  LOADA(13, 832)  LOADA(14, 896)  LOADA(15, 960)
        LOADA(16, 1024) LOADA(17, 1088) LOADA(18, 1152) LOADA(19, 1216)
        LOADA(20, 1280) LOADA(21, 1344) LOADA(22, 1408) LOADA(23, 1472)
        LOADA(24, 1536) LOADA(25, 1600) LOADA(26, 1664) LOADA(27, 1728)
        LOADA(28, 1792) LOADA(29, 1856) LOADA(30, 1920) LOADA(31, 1984)

        // ---- x(t+1) prefetch (youngest; consumed NEXT step) ----
        int tn = (t + 1 < T_DIM) ? (t + 1) : t;
#pragma unroll
        for (int nt = 0; nt < 2; ++nt)
#pragma unroll
            for (int i = 0; i < 4; ++i) {
                const float* xp = input + ((size_t)(brow0 + i) * T_DIM + tn) * N_DIM + jc[nt];
                LOADX(nt * 4 + i, xp)
            }

        f32x4 a0e = {0.f, 0.f, 0.f, 0.f};
        f32x4 a0o = {0.f, 0.f, 0.f, 0.f};
        f32x4 a1e = {0.f, 0.f, 0.f, 0.f};
        f32x4 a1o = {0.f, 0.f, 0.f, 0.f};

        // 41 outstanding (1 poll + 32 a + 8 x); oldest-first retirement:
        asm volatile("s_waitcnt vmcnt(32)" ::: "memory");   // poll + a0..7 done
        __builtin_amdgcn_sched_barrier(0);
        MFMA_S(0, a0e, a1e) MFMA_S(1, a0o, a1o) MFMA_S(2, a0e, a1e) MFMA_S(3, a0o, a1o)
        MFMA_S(4, a0e, a1e) MFMA_S(5, a0o, a1o) MFMA_S(6, a0e, a1e) MFMA_S(7, a0o, a1o)
        asm volatile("s_waitcnt vmcnt(24)" ::: "memory");   // a8..15 done
        __builtin_amdgcn_sched_barrier(0);
        MFMA_S(8, a0e, a1e)  MFMA_S(9, a0o, a1o)  MFMA_S(10, a0e, a1e) MFMA_S(11, a0o, a1o)
        MFMA_S(12, a0e, a1e) MFMA_S(13, a0o, a1o) MFMA_S(14, a0e, a1e) MFMA_S(15, a0o, a1o)
        asm volatile("s_waitcnt vmcnt(16)" ::: "memory");   // a16..23 done
        __builtin_amdgcn_sched_barrier(0);
        MFMA_S(16, a0e, a1e) MFMA_S(17, a0o, a1o) MFMA_S(18, a0e, a1e) MFMA_S(19, a0o, a1o)
        MFMA_S(20, a0e, a1e) MFMA_S(21, a0o, a1o) MFMA_S(22, a0e, a1e) MFMA_S(23, a0o, a1o)
        asm volatile("s_waitcnt vmcnt(8)" ::: "memory");    // a24..31 done (x outstanding)
        __builtin_amdgcn_sched_barrier(0);
        MFMA_S(24, a0e, a1e) MFMA_S(25, a0o, a1o) MFMA_S(26, a0e, a1e) MFMA_S(27, a0o, a1o)
        MFMA_S(28, a0e, a1e) MFMA_S(29, a0o, a1o) MFMA_S(30, a0e, a1e) MFMA_S(31, a0o, a1o)

        f32x4 acc0 = a0e + a0o;
        f32x4 acc1 = a1e + a1o;

        // ---- h update + activation (x(t) already in registers) ----
        float a[8];
#pragma unroll
        for (int i = 0; i < 4; ++i) {
            float hn;
            hn = 0.9f * h[0 + i] + 0.1f * (acc0[i] + x[0 + i]); h[0 + i] = hn; a[0 + i] = ftanh(hn);
            hn = 0.9f * h[4 + i] + 0.1f * (acc1[i] + x[4 + i]); h[4 + i] = hn; a[4 + i] = ftanh(hn);
        }

        // publish a_{t+1}, then out_hidden (plain stores, ack fast), then one
        // drain covering everything, then the tag — next poll starts clean.
        if (t + 1 < T_DIM) {
#pragma unroll
            for (int nt = 0; nt < 2; ++nt)
                publish_tile(anext, &a[nt * 4], brow0, jc[nt], l);
        }
#pragma unroll
        for (int nt = 0; nt < 2; ++nt)
#pragma unroll
            for (int i = 0; i < 4; ++i)
                out_hidden[((size_t)t * B_DIM + (brow0 + i)) * N_DIM + jc[nt]] = a[nt * 4 + i];

        asm volatile("s_waitcnt vmcnt(0)" ::: "memory");    // drain all (incl x(t+1))
        asm volatile("" :: "v"(pv0), "v"(pv1));             // keep poll regs live to here
#pragma unroll
        for (int k = 0; k < 8; ++k) x[k] = xn[k];

        if (t + 1 < T_DIM)
            push_tag(mbox, w, g, (unsigned)(t + 2), l);
    }
}

__global__ void __launch_bounds__(256) geo_kernel(
    const float* __restrict__ hid,
    const float* __restrict__ gW,
    const float* __restrict__ gb,
    const float* __restrict__ rW,
    float* __restrict__ geo,
    float* __restrict__ ro)
{
    int row = blockIdx.x * 4 + (threadIdx.x >> 6);
    int l = threadIdx.x & 63;
    const float* hrow = hid + (size_t)row * N_DIM;
    float a0 = 0.f, a1 = 0.f;
#pragma unroll
    for (int i = 0; i < N_DIM / 64; ++i) {
        int idx = i * 64 + l;
        float th = tanhf(hrow[idx]);
        a0 += th * gW[idx];
        a1 += th * gW[N_DIM + idx];
    }
#pragma unroll
    for (int off = 32; off; off >>= 1) {
        a0 += __shfl_down(a0, off);
        a1 += __shfl_down(a1, off);
    }
    if (l == 0) {
        float g0 = a0 + gb[0];
        float g1 = a1 + gb[1];
        geo[(size_t)row * 2 + 0] = g0;
        geo[(size_t)row * 2 + 1] = g1;
#pragma unroll
        for (int m = 0; m < 6; ++m)
            ro[(size_t)row * 6 + m] = g0 * rW[m * 2] + g1 * rW[m * 2 + 1];
    }
}

extern "C" void kernel_launch(void* const* d_in, const int* in_sizes, int n_in,
                              void* d_out, int out_size, void* d_ws, size_t ws_size,
                              hipStream_t stream) {
    const float* hidden0 = (const float*)d_in[0];
    const float* input   = (const float*)d_in[1];
    const float* lv      = (const float*)d_in[2];
    const float* rv      = (const float*)d_in[3];
    const float* noise   = (const float*)d_in[4];
    const float* gW      = (const float*)d_in[5];
    const float* gb      = (const float*)d_in[6];
    const float* rW      = (const float*)d_in[7];

    float* out_hidden = (float*)d_out;
    float* geo = out_hidden + (size_t)T_DIM * B_DIM * N_DIM;
    float* ro  = geo + (size_t)T_DIM * B_DIM * 2;

    unsigned short* wf    = (unsigned short*)d_ws;                  // 2 MB
    unsigned short* abuf0 = wf + (size_t)64 * 32 * 64 * 8;          // 128 KB
    unsigned short* abuf1 = abuf0 + (size_t)B_DIM * N_DIM;          // 128 KB
    unsigned* mbox = (unsigned*)(abuf1 + (size_t)B_DIM * N_DIM);    // 16 KB

    build_wf<<<2048, 64, 0, stream>>>(lv, rv, noise, wf, mbox);

    void* args[] = { (void*)&hidden0, (void*)&input, (void*)&wf,
                     (void*)&out_hidden, (void*)&abuf0, (void*)&abuf1, (void*)&mbox };
    hipError_t e = hipLaunchCooperativeKernel((const void*)rnn_recurrence,
                                              dim3(NBLK), dim3(64), args, 0, stream);
    if (e != hipSuccess) {
        rnn_recurrence<<<dim3(NBLK), dim3(64), 0, stream>>>(
            hidden0, input, wf, out_hidden, abuf0, abuf1, mbox);
    }

    geo_kernel<<<(T_DIM * B_DIM) / 4, 256, 0, stream>>>(out_hidden, gW, gb, rW, geo, ro);
}